// Round 11
// baseline (62.998 us; speedup 1.0000x reference)
//
#include <hip/hip_runtime.h>
#include <hip/hip_bf16.h>

#define BATCH   16384
#define NTAGS   1024
#define DIM     64
#define HID     128
#define REP     4          // phase-1 repeat for profiling visibility (exact /4 at end)

typedef __attribute__((ext_vector_type(8))) short bf16x8;
typedef __attribute__((ext_vector_type(4))) float f32x4;

__device__ __forceinline__ unsigned short f2bf(float v) {
    unsigned u = __builtin_bit_cast(unsigned, v);
    return (unsigned short)((u + 0x7FFFu + ((u >> 16) & 1u)) >> 16);   // RNE
}

// ---------------------------------------------------------------------------
// prep (R3-verified): pack S_emb and Wfc[0:192] into bf16 16x16x32
// B-fragment-linear layouts (col = lane&15, k = (lane>>4)*8 + j).
// ---------------------------------------------------------------------------
__global__ __launch_bounds__(256) void prep_pack(const float* __restrict__ S,
                                                 const float* __restrict__ Wfc,
                                                 unsigned short* __restrict__ Spack,
                                                 unsigned short* __restrict__ Wp)
{
    int tid = blockIdx.x * 256 + threadIdx.x;   // 0..90111
    if (tid < 65536) {
        int j = tid & 7, l = (tid >> 3) & 63, nf = (tid >> 9) & 3, ks = tid >> 11;
        int k = ks * 32 + (l >> 4) * 8 + j;
        int d = nf * 16 + (l & 15);
        Spack[tid] = f2bf(S[k * 64 + d]);
    } else if (tid < 65536 + 24576) {
        int t2 = tid - 65536;                   // 0..24575
        int j = t2 & 7, l = (t2 >> 3) & 63, ct = (t2 >> 9) & 7, kt = t2 >> 12;
        int k = kt * 32 + (l >> 4) * 8 + j;     // 0..191
        int col = ct * 16 + (l & 15);
        Wp[t2] = f2bf(Wfc[k * 128 + col]);
    }
}

// ---------------------------------------------------------------------------
// fused (R3 structure), with phase 1 repeated REP times for profiling.
// Accumulators sum REP identical passes, then scale by 1/REP (exact).
// ---------------------------------------------------------------------------
__global__ __launch_bounds__(256) void fused_kernel(
    const int* __restrict__ questions, const int* __restrict__ T,
    const float* __restrict__ dfeat, const float* __restrict__ Qemb,
    const float* __restrict__ Wdiff, const float* __restrict__ bdiff,
    const float* __restrict__ Wfc, const float* __restrict__ bfc,
    const float* __restrict__ Wout, const float* __restrict__ bout,
    const unsigned short* __restrict__ Spack, const unsigned short* __restrict__ Wp,
    float* __restrict__ out_e, float* __restrict__ out_p)
{
    __shared__ alignas(16) float accred[4][16][68];
    __shared__ float cntred[4][16];
    __shared__ alignas(16) unsigned short zb[16][200];
    __shared__ float scal[16][3];
    __shared__ float pacc[16][4];

    const int tid  = threadIdx.x;
    const int lane = tid & 63;
    const int wid  = tid >> 6;
    const int g    = lane >> 4;
    const int rl   = lane & 15;
    const int rb   = blockIdx.x * 16;

    // ---- phase 1: T @ S over this wave's K-quarter, REP passes --------------
    f32x4 a0{}, a1{}, a2{}, a3{}, ac{};
    bf16x8 ones;
#pragma unroll
    for (int j = 0; j < 8; ++j) ones[j] = (short)0x3F80;

    const int* tp = T + (size_t)(rb + rl) * 1024 + wid * 256 + g * 8;
    const unsigned short* sp = Spack + (size_t)wid * 8 * 2048 + lane * 8;

    for (int rep = 0; rep < REP; ++rep) {
        asm volatile("" ::: "memory");      // forbid load CSE across passes
#pragma unroll
        for (int ks = 0; ks < 8; ++ks) {
            int4 t0 = *(const int4*)(tp + ks * 32);
            int4 t1 = *(const int4*)(tp + ks * 32 + 4);
            bf16x8 af;
            af[0] = (short)((-t0.x) & 0x3F80);
            af[1] = (short)((-t0.y) & 0x3F80);
            af[2] = (short)((-t0.z) & 0x3F80);
            af[3] = (short)((-t0.w) & 0x3F80);
            af[4] = (short)((-t1.x) & 0x3F80);
            af[5] = (short)((-t1.y) & 0x3F80);
            af[6] = (short)((-t1.z) & 0x3F80);
            af[7] = (short)((-t1.w) & 0x3F80);

            const unsigned short* s2 = sp + ks * 2048;
            bf16x8 b0 = *(const bf16x8*)(s2);
            bf16x8 b1 = *(const bf16x8*)(s2 + 512);
            bf16x8 b2 = *(const bf16x8*)(s2 + 1024);
            bf16x8 b3 = *(const bf16x8*)(s2 + 1536);

            a0 = __builtin_amdgcn_mfma_f32_16x16x32_bf16(af, b0, a0, 0, 0, 0);
            a1 = __builtin_amdgcn_mfma_f32_16x16x32_bf16(af, b1, a1, 0, 0, 0);
            a2 = __builtin_amdgcn_mfma_f32_16x16x32_bf16(af, b2, a2, 0, 0, 0);
            a3 = __builtin_amdgcn_mfma_f32_16x16x32_bf16(af, b3, a3, 0, 0, 0);
            ac = __builtin_amdgcn_mfma_f32_16x16x32_bf16(af, ones, ac, 0, 0, 0);
        }
    }
    const float rscale = 1.0f / (float)REP;   // exact (REP = power of 2)
    a0 *= rscale; a1 *= rscale; a2 *= rscale; a3 *= rscale; ac *= rscale;

    // D layout: col = lane&15, row = (lane>>4)*4 + r
#pragma unroll
    for (int r = 0; r < 4; ++r) {
        int row = g * 4 + r;
        accred[wid][row][rl]      = a0[r];
        accred[wid][row][16 + rl] = a1[r];
        accred[wid][row][32 + rl] = a2[r];
        accred[wid][row][48 + rl] = a3[r];
    }
    if (rl == 0) {
#pragma unroll
        for (int r = 0; r < 4; ++r) cntred[wid][g * 4 + r] = ac[r];
    }
    __syncthreads();

    // ---- phase 2: combine partials, build z (bf16) --------------------------
    {
        int r = tid >> 4, c16 = tid & 15, d0 = c16 * 4;
        float c = cntred[0][r] + cntred[1][r] + cntred[2][r] + cntred[3][r];
        float inv = 1.f / c;
        float4 m0 = *(const float4*)&accred[0][r][d0];
        float4 m1 = *(const float4*)&accred[1][r][d0];
        float4 m2 = *(const float4*)&accred[2][r][d0];
        float4 m3 = *(const float4*)&accred[3][r][d0];
        float mu[4];
        mu[0] = (m0.x + m1.x + m2.x + m3.x) * inv;
        mu[1] = (m0.y + m1.y + m2.y + m3.y) * inv;
        mu[2] = (m0.z + m1.z + m2.z + m3.z) * inv;
        mu[3] = (m0.w + m1.w + m2.w + m3.w) * inv;

        int qi = questions[rb + r];
        float4 q4 = *(const float4*)(Qemb + (size_t)qi * 64 + d0);
        float q[4] = {q4.x, q4.y, q4.z, q4.w};

        float f0 = dfeat[(rb + r) * 3 + 0];
        float f1 = dfeat[(rb + r) * 3 + 1];
        float f2 = dfeat[(rb + r) * 3 + 2];
        float aa[4];
#pragma unroll
        for (int d = 0; d < 4; ++d)
            aa[d] = bdiff[d0 + d] + f0 * Wdiff[d0 + d] + f1 * Wdiff[64 + d0 + d]
                  + f2 * Wdiff[128 + d0 + d];

        ushort4 qv, mv, av;
        qv.x = f2bf(q[0]);  qv.y = f2bf(q[1]);  qv.z = f2bf(q[2]);  qv.w = f2bf(q[3]);
        mv.x = f2bf(mu[0]); mv.y = f2bf(mu[1]); mv.z = f2bf(mu[2]); mv.w = f2bf(mu[3]);
        av.x = f2bf(aa[0]); av.y = f2bf(aa[1]); av.z = f2bf(aa[2]); av.w = f2bf(aa[3]);
        *(ushort4*)&zb[r][d0]       = qv;
        *(ushort4*)&zb[r][64 + d0]  = mv;
        *(ushort4*)&zb[r][128 + d0] = av;

        float s12 = 0.f, s13 = 0.f, s23 = 0.f;
#pragma unroll
        for (int d = 0; d < 4; ++d) {
            s12 += q[d] * mu[d];
            s13 += q[d] * aa[d];
            s23 += mu[d] * aa[d];
        }
#pragma unroll
        for (int off = 1; off < 16; off <<= 1) {
            s12 += __shfl_xor(s12, off);
            s13 += __shfl_xor(s13, off);
            s23 += __shfl_xor(s23, off);
        }
        if (c16 == 0) { scal[r][0] = s12; scal[r][1] = s13; scal[r][2] = s23; }
    }
    __syncthreads();

    // ---- phase 3: tail GEMM (K=192) + epilogue ------------------------------
    {
        bf16x8 afr[6];
#pragma unroll
        for (int kt = 0; kt < 6; ++kt)
            afr[kt] = *(const bf16x8*)&zb[rl][kt * 32 + g * 8];

        float pr0 = 0.f, pr1 = 0.f, pr2 = 0.f, pr3 = 0.f;
#pragma unroll
        for (int c2 = 0; c2 < 2; ++c2) {
            int ct = wid * 2 + c2;
            f32x4 e{};
            const unsigned short* wp = Wp + (size_t)ct * 512 + lane * 8;
#pragma unroll
            for (int kt = 0; kt < 6; ++kt) {
                bf16x8 bfr = *(const bf16x8*)(wp + (size_t)kt * 4096);
                e = __builtin_amdgcn_mfma_f32_16x16x32_bf16(afr[kt], bfr, e, 0, 0, 0);
            }
            int h = ct * 16 + rl;
            float w192 = Wfc[192 * 128 + h];
            float w193 = Wfc[193 * 128 + h];
            float w194 = Wfc[194 * 128 + h];
            float bb = bfc[h];
            float wo = Wout[h];
#pragma unroll
            for (int r = 0; r < 4; ++r) {
                int row = g * 4 + r;
                float ev = e[r] + bb + scal[row][0] * w192 + scal[row][1] * w193
                         + scal[row][2] * w194;
                ev = ev > 0.f ? ev : 0.f;
                out_e[(size_t)(rb + row) * 128 + h] = ev;
                float pc = ev * wo;
                if (r == 0) pr0 += pc; else if (r == 1) pr1 += pc;
                else if (r == 2) pr2 += pc; else pr3 += pc;
            }
        }
#pragma unroll
        for (int off = 1; off < 16; off <<= 1) {
            pr0 += __shfl_xor(pr0, off);
            pr1 += __shfl_xor(pr1, off);
            pr2 += __shfl_xor(pr2, off);
            pr3 += __shfl_xor(pr3, off);
        }
        if (rl == 0) {
            pacc[g * 4 + 0][wid] = pr0;
            pacc[g * 4 + 1][wid] = pr1;
            pacc[g * 4 + 2][wid] = pr2;
            pacc[g * 4 + 3][wid] = pr3;
        }
    }
    __syncthreads();
    if (tid < 16) {
        float v = pacc[tid][0] + pacc[tid][1] + pacc[tid][2] + pacc[tid][3] + bout[0];
        out_p[rb + tid] = 1.f / (1.f + expf(-v));
    }
}

// ---------------------------------------------------------------------------
extern "C" void kernel_launch(void* const* d_in, const int* in_sizes, int n_in,
                              void* d_out, int out_size, void* d_ws, size_t ws_size,
                              hipStream_t stream)
{
    const int*   questions = (const int*)d_in[0];
    const int*   T         = (const int*)d_in[1];
    const float* dfeat     = (const float*)d_in[2];
    const float* Qemb      = (const float*)d_in[3];
    const float* Semb      = (const float*)d_in[4];
    const float* Wdiff     = (const float*)d_in[5];
    const float* bdiff     = (const float*)d_in[6];
    const float* Wfc       = (const float*)d_in[7];
    const float* bfc       = (const float*)d_in[8];
    const float* Wout      = (const float*)d_in[9];
    const float* bout      = (const float*)d_in[10];

    char* ws = (char*)d_ws;
    unsigned short* Spack = (unsigned short*)ws;             // 128 KiB
    unsigned short* Wp    = (unsigned short*)(ws + 131072);  // 48 KiB

    float* out_e = (float*)d_out;
    float* out_p = out_e + (size_t)BATCH * HID;

    hipLaunchKernelGGL(prep_pack, dim3(352), dim3(256), 0, stream, Semb, Wfc, Spack, Wp);
    hipLaunchKernelGGL(fused_kernel, dim3(BATCH / 16), dim3(256), 0, stream,
                       questions, T, dfeat, Qemb, Wdiff, bdiff, Wfc, bfc, Wout, bout,
                       Spack, Wp, out_e, out_p);
}

// Round 12
// 28.016 us; speedup vs baseline: 2.2487x; 2.2487x over previous
//
#include <hip/hip_runtime.h>
#include <hip/hip_bf16.h>

#define BATCH   16384
#define NTAGS   1024
#define DIM     64
#define HID     128

typedef __attribute__((ext_vector_type(8))) short bf16x8;
typedef __attribute__((ext_vector_type(4))) float f32x4;

__device__ __forceinline__ unsigned short f2bf(float v) {
    unsigned u = __builtin_bit_cast(unsigned, v);
    return (unsigned short)((u + 0x7FFFu + ((u >> 16) & 1u)) >> 16);   // RNE
}

// ---------------------------------------------------------------------------
// prep (R3-verified): pack S_emb and Wfc[0:192] into bf16 16x16x32
// B-fragment-linear layouts (col = lane&15, k = (lane>>4)*8 + j).
// ---------------------------------------------------------------------------
__global__ __launch_bounds__(256) void prep_pack(const float* __restrict__ S,
                                                 const float* __restrict__ Wfc,
                                                 unsigned short* __restrict__ Spack,
                                                 unsigned short* __restrict__ Wp)
{
    int tid = blockIdx.x * 256 + threadIdx.x;   // 0..90111
    if (tid < 65536) {
        int j = tid & 7, l = (tid >> 3) & 63, nf = (tid >> 9) & 3, ks = tid >> 11;
        int k = ks * 32 + (l >> 4) * 8 + j;
        int d = nf * 16 + (l & 15);
        Spack[tid] = f2bf(S[k * 64 + d]);
    } else if (tid < 65536 + 24576) {
        int t2 = tid - 65536;                   // 0..24575
        int j = t2 & 7, l = (t2 >> 3) & 63, ct = (t2 >> 9) & 7, kt = t2 >> 12;
        int k = kt * 32 + (l >> 4) * 8 + j;     // 0..191
        int col = ct * 16 + (l & 15);
        Wp[t2] = f2bf(Wfc[k * 128 + col]);
    }
}

// ---------------------------------------------------------------------------
// fused (R3 structure) + tail-operand PREFETCH:
//   At kernel start each thread issues its tail loads (Qemb gather chain,
//   dfeat, 12 Wp fragments, 10 epilogue scalars) so their latency hides
//   under phase 1's ~11.5 us BW-bound T stream. Counts via int adds.
// ---------------------------------------------------------------------------
__global__ __launch_bounds__(256, 3) void fused_kernel(
    const int* __restrict__ questions, const int* __restrict__ T,
    const float* __restrict__ dfeat, const float* __restrict__ Qemb,
    const float* __restrict__ Wdiff, const float* __restrict__ bdiff,
    const float* __restrict__ Wfc, const float* __restrict__ bfc,
    const float* __restrict__ Wout, const float* __restrict__ bout,
    const unsigned short* __restrict__ Spack, const unsigned short* __restrict__ Wp,
    float* __restrict__ out_e, float* __restrict__ out_p)
{
    __shared__ alignas(16) float accred[4][16][68];
    __shared__ float cntred[4][16];
    __shared__ alignas(16) unsigned short zb[16][200];
    __shared__ float scal[16][3];
    __shared__ float pacc[16][4];

    const int tid  = threadIdx.x;
    const int lane = tid & 63;
    const int wid  = tid >> 6;
    const int g    = lane >> 4;
    const int rl   = lane & 15;
    const int rb   = blockIdx.x * 16;

    // ---- PREFETCH tail operands (issued before phase 1) ---------------------
    const int pr_r = tid >> 4, pr_c = tid & 15, pr_d0 = pr_c * 4;
    const int qi = questions[rb + pr_r];
    const float4 q4 = *(const float4*)(Qemb + (size_t)qi * 64 + pr_d0);
    const float pf0 = dfeat[(rb + pr_r) * 3 + 0];
    const float pf1 = dfeat[(rb + pr_r) * 3 + 1];
    const float pf2 = dfeat[(rb + pr_r) * 3 + 2];

    bf16x8 wpf[12];
    float w192v[2], w193v[2], w194v[2], bbv[2], wov[2];
#pragma unroll
    for (int c2 = 0; c2 < 2; ++c2) {
        int ct = wid * 2 + c2;
        const unsigned short* wpb = Wp + (size_t)ct * 512 + lane * 8;
#pragma unroll
        for (int kt = 0; kt < 6; ++kt)
            wpf[c2 * 6 + kt] = *(const bf16x8*)(wpb + (size_t)kt * 4096);
        int h = ct * 16 + rl;
        w192v[c2] = Wfc[192 * 128 + h];
        w193v[c2] = Wfc[193 * 128 + h];
        w194v[c2] = Wfc[194 * 128 + h];
        bbv[c2]   = bfc[h];
        wov[c2]   = Wout[h];
    }

    // ---- phase 1: T @ S over this wave's K-quarter --------------------------
    f32x4 a0{}, a1{}, a2{}, a3{};
    int c = 0;
    {
        const int* tp = T + (size_t)(rb + rl) * 1024 + wid * 256 + g * 8;
        const unsigned short* sp = Spack + (size_t)wid * 8 * 2048 + lane * 8;

#pragma unroll
        for (int ks = 0; ks < 8; ++ks) {
            int4 t0 = *(const int4*)(tp + ks * 32);
            int4 t1 = *(const int4*)(tp + ks * 32 + 4);
            c += t0.x + t0.y + t0.z + t0.w + t1.x + t1.y + t1.z + t1.w;
            bf16x8 af;
            af[0] = (short)((-t0.x) & 0x3F80);
            af[1] = (short)((-t0.y) & 0x3F80);
            af[2] = (short)((-t0.z) & 0x3F80);
            af[3] = (short)((-t0.w) & 0x3F80);
            af[4] = (short)((-t1.x) & 0x3F80);
            af[5] = (short)((-t1.y) & 0x3F80);
            af[6] = (short)((-t1.z) & 0x3F80);
            af[7] = (short)((-t1.w) & 0x3F80);

            const unsigned short* s2 = sp + ks * 2048;
            bf16x8 b0 = *(const bf16x8*)(s2);
            bf16x8 b1 = *(const bf16x8*)(s2 + 512);
            bf16x8 b2 = *(const bf16x8*)(s2 + 1024);
            bf16x8 b3 = *(const bf16x8*)(s2 + 1536);

            a0 = __builtin_amdgcn_mfma_f32_16x16x32_bf16(af, b0, a0, 0, 0, 0);
            a1 = __builtin_amdgcn_mfma_f32_16x16x32_bf16(af, b1, a1, 0, 0, 0);
            a2 = __builtin_amdgcn_mfma_f32_16x16x32_bf16(af, b2, a2, 0, 0, 0);
            a3 = __builtin_amdgcn_mfma_f32_16x16x32_bf16(af, b3, a3, 0, 0, 0);
        }
    }
    // counts: reduce partials across g (k-slices) for row rl
    c += __shfl_xor(c, 16);
    c += __shfl_xor(c, 32);
    if (lane < 16) cntred[wid][lane] = (float)c;

    // D layout: col = lane&15, row = (lane>>4)*4 + r
#pragma unroll
    for (int r = 0; r < 4; ++r) {
        int row = g * 4 + r;
        accred[wid][row][rl]      = a0[r];
        accred[wid][row][16 + rl] = a1[r];
        accred[wid][row][32 + rl] = a2[r];
        accred[wid][row][48 + rl] = a3[r];
    }
    __syncthreads();

    // ---- phase 2: combine partials, build z (bf16) --------------------------
    {
        int r = pr_r, c16 = pr_c, d0 = pr_d0;
        float cc = cntred[0][r] + cntred[1][r] + cntred[2][r] + cntred[3][r];
        float inv = 1.f / cc;
        float4 m0 = *(const float4*)&accred[0][r][d0];
        float4 m1 = *(const float4*)&accred[1][r][d0];
        float4 m2 = *(const float4*)&accred[2][r][d0];
        float4 m3 = *(const float4*)&accred[3][r][d0];
        float mu[4];
        mu[0] = (m0.x + m1.x + m2.x + m3.x) * inv;
        mu[1] = (m0.y + m1.y + m2.y + m3.y) * inv;
        mu[2] = (m0.z + m1.z + m2.z + m3.z) * inv;
        mu[3] = (m0.w + m1.w + m2.w + m3.w) * inv;

        float q[4] = {q4.x, q4.y, q4.z, q4.w};
        float aa[4];
#pragma unroll
        for (int d = 0; d < 4; ++d)
            aa[d] = bdiff[d0 + d] + pf0 * Wdiff[d0 + d] + pf1 * Wdiff[64 + d0 + d]
                  + pf2 * Wdiff[128 + d0 + d];

        ushort4 qv, mv, av;
        qv.x = f2bf(q[0]);  qv.y = f2bf(q[1]);  qv.z = f2bf(q[2]);  qv.w = f2bf(q[3]);
        mv.x = f2bf(mu[0]); mv.y = f2bf(mu[1]); mv.z = f2bf(mu[2]); mv.w = f2bf(mu[3]);
        av.x = f2bf(aa[0]); av.y = f2bf(aa[1]); av.z = f2bf(aa[2]); av.w = f2bf(aa[3]);
        *(ushort4*)&zb[r][d0]       = qv;
        *(ushort4*)&zb[r][64 + d0]  = mv;
        *(ushort4*)&zb[r][128 + d0] = av;

        float s12 = 0.f, s13 = 0.f, s23 = 0.f;
#pragma unroll
        for (int d = 0; d < 4; ++d) {
            s12 += q[d] * mu[d];
            s13 += q[d] * aa[d];
            s23 += mu[d] * aa[d];
        }
#pragma unroll
        for (int off = 1; off < 16; off <<= 1) {
            s12 += __shfl_xor(s12, off);
            s13 += __shfl_xor(s13, off);
            s23 += __shfl_xor(s23, off);
        }
        if (c16 == 0) { scal[r][0] = s12; scal[r][1] = s13; scal[r][2] = s23; }
    }
    __syncthreads();

    // ---- phase 3: tail GEMM (K=192) + epilogue (all operands in registers) --
    {
        bf16x8 afr[6];
#pragma unroll
        for (int kt = 0; kt < 6; ++kt)
            afr[kt] = *(const bf16x8*)&zb[rl][kt * 32 + g * 8];

        float pr0 = 0.f, pr1 = 0.f, pr2 = 0.f, pr3 = 0.f;
#pragma unroll
        for (int c2 = 0; c2 < 2; ++c2) {
            int ct = wid * 2 + c2;
            f32x4 e{};
#pragma unroll
            for (int kt = 0; kt < 6; ++kt)
                e = __builtin_amdgcn_mfma_f32_16x16x32_bf16(afr[kt], wpf[c2 * 6 + kt], e, 0, 0, 0);
            int h = ct * 16 + rl;
#pragma unroll
            for (int r = 0; r < 4; ++r) {
                int row = g * 4 + r;
                float ev = e[r] + bbv[c2] + scal[row][0] * w192v[c2]
                         + scal[row][1] * w193v[c2] + scal[row][2] * w194v[c2];
                ev = ev > 0.f ? ev : 0.f;
                out_e[(size_t)(rb + row) * 128 + h] = ev;
                float pc = ev * wov[c2];
                if (r == 0) pr0 += pc; else if (r == 1) pr1 += pc;
                else if (r == 2) pr2 += pc; else pr3 += pc;
            }
        }
#pragma unroll
        for (int off = 1; off < 16; off <<= 1) {
            pr0 += __shfl_xor(pr0, off);
            pr1 += __shfl_xor(pr1, off);
            pr2 += __shfl_xor(pr2, off);
            pr3 += __shfl_xor(pr3, off);
        }
        if (rl == 0) {
            pacc[g * 4 + 0][wid] = pr0;
            pacc[g * 4 + 1][wid] = pr1;
            pacc[g * 4 + 2][wid] = pr2;
            pacc[g * 4 + 3][wid] = pr3;
        }
    }
    __syncthreads();
    if (tid < 16) {
        float v = pacc[tid][0] + pacc[tid][1] + pacc[tid][2] + pacc[tid][3] + bout[0];
        out_p[rb + tid] = 1.f / (1.f + expf(-v));
    }
}

// ---------------------------------------------------------------------------
extern "C" void kernel_launch(void* const* d_in, const int* in_sizes, int n_in,
                              void* d_out, int out_size, void* d_ws, size_t ws_size,
                              hipStream_t stream)
{
    const int*   questions = (const int*)d_in[0];
    const int*   T         = (const int*)d_in[1];
    const float* dfeat     = (const float*)d_in[2];
    const float* Qemb      = (const float*)d_in[3];
    const float* Semb      = (const float*)d_in[4];
    const float* Wdiff     = (const float*)d_in[5];
    const float* bdiff     = (const float*)d_in[6];
    const float* Wfc       = (const float*)d_in[7];
    const float* bfc       = (const float*)d_in[8];
    const float* Wout      = (const float*)d_in[9];
    const float* bout      = (const float*)d_in[10];

    char* ws = (char*)d_ws;
    unsigned short* Spack = (unsigned short*)ws;             // 128 KiB
    unsigned short* Wp    = (unsigned short*)(ws + 131072);  // 48 KiB

    float* out_e = (float*)d_out;
    float* out_p = out_e + (size_t)BATCH * HID;

    hipLaunchKernelGGL(prep_pack, dim3(352), dim3(256), 0, stream, Semb, Wfc, Spack, Wp);
    hipLaunchKernelGGL(fused_kernel, dim3(BATCH / 16), dim3(256), 0, stream,
                       questions, T, dfeat, Qemb, Wdiff, bdiff, Wfc, bfc, Wout, bout,
                       Spack, Wp, out_e, out_p);
}